// Round 1
// baseline (198.848 us; speedup 1.0000x reference)
//
#include <hip/hip_runtime.h>
#include <hip/hip_bf16.h>
#include <math.h>

#define B_SZ 8192
#define I_SZ 1024
#define O_SZ 1024
#define NCP  6

typedef __attribute__((ext_vector_type(8))) short bf16x8;
typedef __attribute__((ext_vector_type(4))) float f32x4;

__device__ __forceinline__ unsigned short f2bf(float f) {
  union { float f; unsigned int u; } v; v.f = f;
  unsigned int u = v.u;
  u += 0x7FFFu + ((u >> 16) & 1u);   // round-to-nearest-even
  return (unsigned short)(u >> 16);
}

__global__ void cvt_f32_to_bf16(const float* __restrict__ src,
                                unsigned short* __restrict__ dst, int n4) {
  int idx = blockIdx.x * blockDim.x + threadIdx.x;
  int stride = gridDim.x * blockDim.x;
  for (int i = idx; i < n4; i += stride) {
    float4 v = reinterpret_cast<const float4*>(src)[i];
    ushort4 o;
    o.x = f2bf(v.x); o.y = f2bf(v.y); o.z = f2bf(v.z); o.w = f2bf(v.w);
    reinterpret_cast<ushort4*>(dst)[i] = o;
  }
}

__device__ __forceinline__ void gload_lds16(const void* g, void* l) {
  __builtin_amdgcn_global_load_lds(
      (const __attribute__((address_space(1))) void*)g,
      (__attribute__((address_space(3))) void*)l, 16, 0, 0);
}

#define BM 128
#define BN 128
#define BK 64

// out[b,o] = sum_j c[b,j] * ( sum_i W[j,o,i]*x[b,i] + bias[j,o] )
// GEMM: A = xb16 [B_SZ][I_SZ] (K wraps mod I_SZ over 6 chunks),
//       B^T = wb16 [NCP][O_SZ][I_SZ]  (row-major [n][k] per chunk)
// per-j partial accumulator scaled by c[row,j] at chunk boundary.
__global__ __launch_bounds__(256, 2) void pfl_gemm(
    const unsigned short* __restrict__ xb,
    const unsigned short* __restrict__ wb,
    const float* __restrict__ phase,
    const float* __restrict__ bias,
    float* __restrict__ out) {
  __shared__ __align__(16) unsigned short Asm[BM * BK];
  __shared__ __align__(16) unsigned short Bsm[BN * BK];
  __shared__ float c_lds[BM][NCP];

  const int nbn = O_SZ / BN;  // 8
  int bid = (int)blockIdx.x;
  int nwg = (int)gridDim.x;   // 512 (divisible by 8)
  int cpx = nwg >> 3;
  int swz = (bid & 7) * cpx + (bid >> 3);  // XCD-contiguous remap
  int brow = (swz / nbn) * BM;
  int bcol = (swz % nbn) * BN;

  int tid = (int)threadIdx.x;
  int lane = tid & 63;
  int wid = tid >> 6;        // 4 waves: 2x2 over the 128x128 tile
  int wr = wid >> 1, wc = wid & 1;

  // ---- Catmull-Rom coefficients for this block's 128 rows ----
  if (tid < BM) {
    float ph = phase[brow + tid];
    const float two_pi = 6.2831855f;           // (float)(2*pi), matches jnp f32
    float pm = fmodf(ph, two_pi);              // ph >= 0, so trunc == floor mod
    float pos = pm * (float)(6.0 / 6.283185307179586);
    float base = floorf(pos);
    int bi = (int)base;
    float t = pos - base;
    float t2 = t * t, t3 = t2 * t;
    float w0 = -0.5f * t + t2 - 0.5f * t3;
    float w1 = 1.0f - 2.5f * t2 + 1.5f * t3;
    float w2 = 0.5f * t + 2.0f * t2 - 1.5f * t3;
    float w3 = -0.5f * t2 + 0.5f * t3;
    float cc[NCP] = {0.f, 0.f, 0.f, 0.f, 0.f, 0.f};
    cc[((bi - 1) % NCP + NCP) % NCP] += w0;
    cc[(bi % NCP + NCP) % NCP]       += w1;
    cc[((bi + 1) % NCP + NCP) % NCP] += w2;
    cc[((bi + 2) % NCP + NCP) % NCP] += w3;
    for (int j = 0; j < NCP; ++j) c_lds[tid][j] = cc[j];
  }

  f32x4 acc[4][4];
  f32x4 part[4][4];
  for (int m = 0; m < 4; ++m)
    for (int n = 0; n < 4; ++n) {
      acc[m][n] = (f32x4){0.f, 0.f, 0.f, 0.f};
      part[m][n] = (f32x4){0.f, 0.f, 0.f, 0.f};
    }

  // staging: per wave-instruction, lane l -> row (base + l/8), col8 (l&7)*8
  const unsigned short* xsrc =
      xb + (size_t)(brow + wid * 8 + (lane >> 3)) * I_SZ + (lane & 7) * 8;
  const unsigned short* wsrc0 =
      wb + (size_t)(bcol + wid * 8 + (lane >> 3)) * I_SZ + (lane & 7) * 8;

  for (int j = 0; j < NCP; ++j) {
    const unsigned short* wsrc = wsrc0 + (size_t)j * O_SZ * I_SZ;
    for (int ks = 0; ks < I_SZ / BK; ++ks) {
      int i0 = ks * BK;
      __syncthreads();  // previous tile's reads done before overwrite
      for (int p = 0; p < 4; ++p) {
        gload_lds16(xsrc + (size_t)p * 32 * I_SZ + i0,
                    &Asm[(wid * 8 + p * 32) * BK]);
        gload_lds16(wsrc + (size_t)p * 32 * I_SZ + i0,
                    &Bsm[(wid * 8 + p * 32) * BK]);
      }
      __syncthreads();  // drains vmcnt: tile resident
      for (int kk = 0; kk < 2; ++kk) {
        bf16x8 af[4], bfr[4];
        int ko = kk * 32 + (lane >> 4) * 8;
        for (int m = 0; m < 4; ++m)
          af[m] = *reinterpret_cast<const bf16x8*>(
              &Asm[(wr * 64 + m * 16 + (lane & 15)) * BK + ko]);
        for (int n = 0; n < 4; ++n)
          bfr[n] = *reinterpret_cast<const bf16x8*>(
              &Bsm[(wc * 64 + n * 16 + (lane & 15)) * BK + ko]);
        for (int m = 0; m < 4; ++m)
          for (int n = 0; n < 4; ++n)
            part[m][n] = __builtin_amdgcn_mfma_f32_16x16x32_bf16(
                af[m], bfr[n], part[m][n], 0, 0, 0);
      }
    }
    // fold this chunk: acc += c[row, j] * part; part = 0
    for (int m = 0; m < 4; ++m) {
      float cj[4];
      for (int r = 0; r < 4; ++r)
        cj[r] = c_lds[wr * 64 + m * 16 + (lane >> 4) * 4 + r][j];
      for (int n = 0; n < 4; ++n) {
        for (int r = 0; r < 4; ++r)
          acc[m][n][r] += cj[r] * part[m][n][r];
        part[m][n] = (f32x4){0.f, 0.f, 0.f, 0.f};
      }
    }
  }

  // ---- epilogue: bias mix + store (f32) ----
  for (int n = 0; n < 4; ++n) {
    int col = bcol + wc * 64 + n * 16 + (lane & 15);
    float b6[NCP];
    for (int j = 0; j < NCP; ++j) b6[j] = bias[j * O_SZ + col];
    for (int m = 0; m < 4; ++m) {
      for (int r = 0; r < 4; ++r) {
        int rloc = wr * 64 + m * 16 + (lane >> 4) * 4 + r;
        float s = 0.f;
        for (int j = 0; j < NCP; ++j) s += c_lds[rloc][j] * b6[j];
        out[(size_t)(brow + rloc) * O_SZ + col] = acc[m][n][r] + s;
      }
    }
  }
}

extern "C" void kernel_launch(void* const* d_in, const int* in_sizes, int n_in,
                              void* d_out, int out_size, void* d_ws, size_t ws_size,
                              hipStream_t stream) {
  (void)in_sizes; (void)n_in; (void)out_size; (void)ws_size;
  const float* x     = (const float*)d_in[0];  // [B, I]
  const float* phase = (const float*)d_in[1];  // [B]
  const float* w     = (const float*)d_in[2];  // [C, O, I]
  const float* bias  = (const float*)d_in[3];  // [C, O]
  float* out = (float*)d_out;                  // [B, O] f32

  unsigned short* xb = (unsigned short*)d_ws;                       // 16 MB
  unsigned short* wb = (unsigned short*)((char*)d_ws +
                        (size_t)B_SZ * I_SZ * sizeof(unsigned short));  // 12 MB

  cvt_f32_to_bf16<<<2048, 256, 0, stream>>>(x, xb, B_SZ * I_SZ / 4);
  cvt_f32_to_bf16<<<1536, 256, 0, stream>>>(w, wb, NCP * O_SZ * I_SZ / 4);

  dim3 grid((B_SZ / BM) * (O_SZ / BN));  // 64*8 = 512
  pfl_gemm<<<grid, 256, 0, stream>>>(xb, wb, phase, bias, out);
}